// Round 6
// baseline (1081.929 us; speedup 1.0000x reference)
//
#include <hip/hip_runtime.h>

// ---------------- problem constants ----------------
#define BQ   8
#define SQ   1569
#define BS   12552      // BQ*SQ
#define DM   768
#define NH   12
#define DH   64
#define TT   8
#define PP   196
#define D4   3072
#define QKVN 2304
#define CCH  24         // CLS split-K chunks
#define CKEY 66         // keys per chunk (24*66 = 1584 >= 1569)
#define MB_PAD 104      // 99 m-blocks padded to multiple of 8 for XCD-stable swizzle

typedef _Float16 f16;
typedef _Float16 f16x8 __attribute__((ext_vector_type(8)));
typedef float    f32x4 __attribute__((ext_vector_type(4)));
typedef unsigned long long u64;

#define AS1 __attribute__((address_space(1)))
#define AS3 __attribute__((address_space(3)))

#define Y_OFF    0ULL
#define QKV_OFF  19279872ULL
#define CTX_OFF  77119488ULL
#define H_OFF    19279872ULL
#define W_OFF    96399360ULL

// ---------------- LayerNorm (wave per row) ----------------
__global__ __launch_bounds__(256) void ln_kernel(const float* __restrict__ x,
                                                 const float* __restrict__ g,
                                                 const float* __restrict__ bta,
                                                 f16* __restrict__ y) {
    int row = blockIdx.x * 4 + (threadIdx.x >> 6);
    int lane = threadIdx.x & 63;
    if (row >= BS) return;
    const float* xr = x + (u64)row * DM;
    float v[12];
    float s = 0.f, s2 = 0.f;
#pragma unroll
    for (int i = 0; i < 12; i++) { v[i] = xr[lane + i * 64]; s += v[i]; s2 += v[i] * v[i]; }
#pragma unroll
    for (int m = 1; m < 64; m <<= 1) { s += __shfl_xor(s, m, 64); s2 += __shfl_xor(s2, m, 64); }
    float mean = s * (1.f / 768.f);
    float var  = s2 * (1.f / 768.f) - mean * mean;
    float rstd = rsqrtf(var + 1e-12f);
    f16* yr = y + (u64)row * DM;
#pragma unroll
    for (int i = 0; i < 12; i++) {
        int c = lane + i * 64;
        yr[c] = (f16)((v[i] - mean) * rstd * g[c] + bta[c]);
    }
}

// ---------------- transpose fp32 -> f16 (dst[c*R+r] = src[r*C+c]) ----------------
__global__ __launch_bounds__(256) void transpose_kernel(const float* __restrict__ src,
                                                        f16* __restrict__ dst,
                                                        int R, int C) {
    __shared__ float tile[32][33];
    int bx = blockIdx.x * 32;
    int by = blockIdx.y * 32;
    int tx = threadIdx.x & 31, ty = threadIdx.x >> 5;
#pragma unroll
    for (int i = 0; i < 4; i++) {
        int r = by + ty + i * 8, c = bx + tx;
        if (r < R && c < C) tile[ty + i * 8][tx] = src[(u64)r * C + c];
    }
    __syncthreads();
#pragma unroll
    for (int i = 0; i < 4; i++) {
        int c = bx + ty + i * 8, r = by + tx;
        if (c < C && r < R) dst[(u64)c * R + r] = (f16)tile[tx][ty + i * 8];
    }
}

// ---------------- concat 3 bias vectors (768 each) ----------------
__global__ __launch_bounds__(256) void bias3_kernel(const float* __restrict__ a,
                                                    const float* __restrict__ b,
                                                    const float* __restrict__ c,
                                                    float* __restrict__ dst) {
    int i = blockIdx.x * 256 + threadIdx.x;
    if (i < 768) { dst[i] = a[i]; dst[i + 768] = b[i]; dst[i + 1536] = c[i]; }
}

// ---------------- GEMM v7: barrier-free per-wave private staging ----------------
// C = A(BSxK,f16) @ Bt^T (Bt NxK f16) + bias [+gelu][+resid]
// Round-5 lesson: fixing bank conflicts inside the 2-barrier structure is null
// (conflicts 7.3M->0, perf WORSE via lost occupancy) -> the critical path is the
// correlated per-iteration vmcnt(0)+syncthreads drain. v7 removes the coupling:
// each wave stages a PRIVATE copy of the A-half (wm) and B-half (wn) it reads
// (4KB+4KB per buffer, dbuf = 16KB/wave, 64KB/block). Zero inter-wave LDS deps
// -> NO barriers; each wave free-runs on its own counted s_waitcnt vmcnt(8)
// (8 staging loads/tile/wave), prefetch distance 2. Race-free by construction.
// Cost: 2x staging traffic (L2-hit-dominated) + 2 blocks/CU (vs ~3) -- traded
// for fully decorrelated wave progress. Granule swizzle kept from v5.2 (verified
// conflict-free + numerics-identical this round; LDS reads are now per-wave
// critical path). M-tail rows CLAMPED so vmcnt counts stay uniform per wave.
template <int NOUT, bool GELU, bool RESID, bool OUTF16>
__global__ __launch_bounds__(256, 2) void gemm_kernel(const f16* __restrict__ A,
                                                      const f16* __restrict__ Bt,
                                                      const float* __restrict__ bias,
                                                      const float* __restrict__ resid,
                                                      float* __restrict__ Cf,
                                                      f16* __restrict__ Ch,
                                                      int K) {
    __shared__ __align__(16) f16 L[4][2][4096];   // [wave][buf][A 4KB | B 4KB]
    int id = blockIdx.x;
    int mb = id % MB_PAD, nb = id / MB_PAD;
    if (mb >= 99) return;
    int tid  = threadIdx.x;
    int lane = tid & 63, wave = tid >> 6;
    int wm = wave >> 1, wn = wave & 1;
    int m0 = mb * 128, n0 = nb * 128;
    int l15 = lane & 15, quad = lane >> 4;

    // staging: instr j covers LDS bytes j*1024 + lane*16 of the wave's half-tile
    // => row j*16 + (lane>>2), lds granule lane&3; global granule is XOR-swizzled
    // by ((row>>1)&3) == ((lane>>3)&3)  (rule #21: linear LDS dest, swizzled src).
    int rq   = lane >> 2;
    int coff = ((lane & 3) ^ ((lane >> 3) & 3)) * 8;
    const f16* ag[4];
    const f16* bg[4];
#pragma unroll
    for (int j = 0; j < 4; j++) {
        int ra = m0 + wm * 64 + j * 16 + rq; if (ra > BS - 1) ra = BS - 1;  // clamp M tail
        ag[j] = A + (u64)ra * K + coff;
        bg[j] = Bt + (u64)(n0 + wn * 64 + j * 16 + rq) * K + coff;
    }
    AS3 char* waveL = (AS3 char*)&L[0][0][0] + wave * 16384;
    // read-side: global granule `quad` of row (i*16+l15) sits at lds granule
    // quad ^ ((l15>>1)&3)  (verified conflict-free + bit-exact in round 5)
    int gsw = (quad ^ ((l15 >> 1) & 3)) * 16;   // byte offset

#define STAGE(BUF, KT) { \
    u64 _ko = (u64)(KT) * 32; \
    AS3 char* _d = waveL + (BUF) * 8192; \
    __builtin_amdgcn_global_load_lds((const AS1 void*)(ag[0] + _ko), (AS3 void*)(_d),        16, 0, 0); \
    __builtin_amdgcn_global_load_lds((const AS1 void*)(ag[1] + _ko), (AS3 void*)(_d + 1024), 16, 0, 0); \
    __builtin_amdgcn_global_load_lds((const AS1 void*)(ag[2] + _ko), (AS3 void*)(_d + 2048), 16, 0, 0); \
    __builtin_amdgcn_global_load_lds((const AS1 void*)(ag[3] + _ko), (AS3 void*)(_d + 3072), 16, 0, 0); \
    __builtin_amdgcn_global_load_lds((const AS1 void*)(bg[0] + _ko), (AS3 void*)(_d + 4096), 16, 0, 0); \
    __builtin_amdgcn_global_load_lds((const AS1 void*)(bg[1] + _ko), (AS3 void*)(_d + 5120), 16, 0, 0); \
    __builtin_amdgcn_global_load_lds((const AS1 void*)(bg[2] + _ko), (AS3 void*)(_d + 6144), 16, 0, 0); \
    __builtin_amdgcn_global_load_lds((const AS1 void*)(bg[3] + _ko), (AS3 void*)(_d + 7168), 16, 0, 0); \
}

    f32x4 acc[4][4];
#pragma unroll
    for (int i = 0; i < 4; i++)
#pragma unroll
        for (int j = 0; j < 4; j++)
#pragma unroll
            for (int r = 0; r < 4; r++) acc[i][j][r] = 0.f;

    // prologue: tiles 0 and 1 in flight (16 loads outstanding, this wave only)
    STAGE(0, 0);
    STAGE(1, 1);

    int nit = K >> 5;
    for (int it = 0; it < nit; it++) {
        int buf = it & 1;
        // wait for tile `it` (oldest 8 of THIS wave's loads); tile it+1 stays in flight.
        // "memory" clobber: LDS reads below cannot hoist above this wait.
        if (it + 1 < nit) { asm volatile("s_waitcnt vmcnt(8)" ::: "memory"); }
        else              { asm volatile("s_waitcnt vmcnt(0)" ::: "memory"); }
        const AS3 char* Ap = waveL + buf * 8192;

        f16x8 af[4], bf[4];
#pragma unroll
        for (int i = 0; i < 4; i++)
            af[i] = *(const AS3 f16x8*)(Ap + (i * 16 + l15) * 64 + gsw);
#pragma unroll
        for (int j = 0; j < 4; j++)
            bf[j] = *(const AS3 f16x8*)(Ap + 4096 + (j * 16 + l15) * 64 + gsw);
        // fragments landed in regs before we overwrite this buffer's LDS via DMA
        asm volatile("s_waitcnt lgkmcnt(0)" ::: "memory");
        if (it + 2 < nit) STAGE(buf, it + 2);

#pragma unroll
        for (int i = 0; i < 4; i++)
#pragma unroll
            for (int j = 0; j < 4; j++)
                acc[i][j] = __builtin_amdgcn_mfma_f32_16x16x32_f16(af[i], bf[j], acc[i][j], 0, 0, 0);
    }
#undef STAGE

#pragma unroll
    for (int i = 0; i < 4; i++) {
#pragma unroll
        for (int j = 0; j < 4; j++) {
            int col = n0 + wn * 64 + j * 16 + l15;
            float bv = bias[col];
#pragma unroll
            for (int r = 0; r < 4; r++) {
                int row = m0 + wm * 64 + i * 16 + quad * 4 + r;
                if (row < BS) {
                    float v = acc[i][j][r] + bv;
                    if (GELU) {
                        // tanh-approx GELU (max dev ~3e-3 from exact erf form):
                        // gelu(x) = x * sigmoid(2*0.7978845608*(x + 0.044715 x^3))
                        float u = 0.7978845608028654f * (v + 0.044715f * v * v * v);
                        float e = __builtin_exp2f(-2.885390081777927f * u);
                        v = v / (1.f + e);
                    }
                    if (RESID) v += resid[(u64)row * NOUT + col];
                    if (OUTF16) Ch[(u64)row * NOUT + col] = (f16)v;
                    else        Cf[(u64)row * NOUT + col] = v;
                }
            }
        }
    }
}

// ---------------- time attention: wave per (b,h,p); 8 queries x 9 keys ----------------
__global__ __launch_bounds__(256) void time_attn_kernel(const f16* __restrict__ qkv,
                                                        f16* __restrict__ ctx) {
    int w = blockIdx.x * 4 + (threadIdx.x >> 6);
    int lane = threadIdx.x & 63;
    int b = w / (NH * PP);
    int rem = w % (NH * PP);
    int h = rem / PP, p = rem % PP;
    u64 bb = (u64)b * SQ;
    int hoff = h * 64 + lane;

    float qv[TT], kv[9], vv[9];
#pragma unroll
    for (int t = 0; t < TT; t++) qv[t] = (float)qkv[(bb + 1 + t * PP + p) * QKVN + hoff];
    kv[0] = (float)qkv[bb * QKVN + 768 + hoff];
    vv[0] = (float)qkv[bb * QKVN + 1536 + hoff];
#pragma unroll
    for (int j = 1; j <= TT; j++) {
        u64 ro = (bb + 1 + (u64)(j - 1) * PP + p) * QKVN;
        kv[j] = (float)qkv[ro + 768 + hoff];
        vv[j] = (float)qkv[ro + 1536 + hoff];
    }
#pragma unroll
    for (int t = 0; t < TT; t++) {
        float s[9];
#pragma unroll
        for (int j = 0; j < 9; j++) {
            float ps = qv[t] * kv[j];
#pragma unroll
            for (int m = 1; m < 64; m <<= 1) ps += __shfl_xor(ps, m, 64);
            s[j] = ps * 0.125f;
        }
        float mx = s[0];
#pragma unroll
        for (int j = 1; j < 9; j++) mx = fmaxf(mx, s[j]);
        float sum = 0.f;
#pragma unroll
        for (int j = 0; j < 9; j++) { s[j] = expf(s[j] - mx); sum += s[j]; }
        float o = 0.f;
#pragma unroll
        for (int j = 0; j < 9; j++) o += s[j] * vv[j];
        o /= sum;
        ctx[(bb + 1 + (u64)t * PP + p) * DM + h * 64 + lane] = (f16)o;
    }
}

// ---------------- CLS attention split-K: part kernel, block per (b,h,chunk) ----------------
__global__ __launch_bounds__(256) void cls_part_kernel(const f16* __restrict__ qkv,
                                                       float* __restrict__ part) {
    int g = blockIdx.x;
    int c = g % CCH, bh = g / CCH;
    int b = bh / NH, h = bh % NH;
    u64 bb = (u64)b * SQ;
    int tid = threadIdx.x, lane = tid & 63, wave = tid >> 6;
    __shared__ float sc[CKEY];
    __shared__ float accbuf[4][64];
    __shared__ float lbuf[4];
    __shared__ float mxs;
    float qd = (float)qkv[bb * QKVN + h * 64 + lane];
    int j0 = c * CKEY;
    int cnt = SQ - j0; if (cnt > CKEY) cnt = CKEY;
    for (int jj = wave; jj < cnt; jj += 4) {
        float p = qd * (float)qkv[(bb + j0 + jj) * QKVN + 768 + h * 64 + lane];
#pragma unroll
        for (int m = 1; m < 64; m <<= 1) p += __shfl_xor(p, m, 64);
        if (lane == 0) sc[jj] = p * 0.125f;
    }
    __syncthreads();
    if (wave == 0) {
        float m = -1e30f;
        for (int j = lane; j < cnt; j += 64) m = fmaxf(m, sc[j]);
#pragma unroll
        for (int s = 1; s < 64; s <<= 1) m = fmaxf(m, __shfl_xor(m, s, 64));
        if (lane == 0) mxs = m;
    }
    __syncthreads();
    float mx = mxs;
    float acc = 0.f, l = 0.f;
    for (int jj = wave; jj < cnt; jj += 4) {
        float w = expf(sc[jj] - mx);
        l += w;
        acc += w * (float)qkv[(bb + j0 + jj) * QKVN + 1536 + h * 64 + lane];
    }
    accbuf[wave][lane] = acc;
    if (lane == 0) lbuf[wave] = l;
    __syncthreads();
    if (tid < 64) {
        float a = accbuf[0][tid] + accbuf[1][tid] + accbuf[2][tid] + accbuf[3][tid];
        float* pb = part + ((u64)bh * CCH + c) * 66;
        if (tid == 0) { pb[0] = mxs; pb[1] = lbuf[0] + lbuf[1] + lbuf[2] + lbuf[3]; }
        pb[2 + tid] = a;
    }
}

// ---------------- CLS attention split-K: combine kernel, wave per (b,h) ----------------
__global__ __launch_bounds__(256) void cls_comb_kernel(const float* __restrict__ part,
                                                       f16* __restrict__ ctx) {
    int w = blockIdx.x * 4 + (threadIdx.x >> 6);
    int lane = threadIdx.x & 63;
    if (w >= BQ * NH) return;
    int b = w / NH, h = w % NH;
    const float* pb = part + (u64)w * CCH * 66;
    float m = (lane < CCH) ? pb[lane * 66] : -1e30f;
#pragma unroll
    for (int s = 1; s < 64; s <<= 1) m = fmaxf(m, __shfl_xor(m, s, 64));
    float l = (lane < CCH) ? pb[lane * 66 + 1] * expf(pb[lane * 66] - m) : 0.f;
#pragma unroll
    for (int s = 1; s < 64; s <<= 1) l += __shfl_xor(l, s, 64);
    float o = 0.f;
    for (int j = 0; j < CCH; j++) {
        float mj = pb[j * 66];
        o += pb[j * 66 + 2 + lane] * expf(mj - m);
    }
    ctx[((u64)b * SQ) * DM + h * 64 + lane] = (f16)(o / l);
}

// ---------------- space attention: MFMA flash, block per (b,h,t) ----------------
__global__ __launch_bounds__(256) void space_attn_kernel(const f16* __restrict__ qkv,
                                                         f16* __restrict__ ctx) {
    int g = blockIdx.x;
    int b = g / (NH * TT);
    int rem = g % (NH * TT);
    int h = rem / TT, t = rem % TT;
    __shared__ __align__(16) f16 Vt[64 * 232];
    __shared__ __align__(16) f16 Ps[4 * 16 * 232];
    u64 bb = (u64)b * SQ;
    int tid = threadIdx.x, lane = tid & 63, wave = tid >> 6;
    int l15 = lane & 15, quad = lane >> 4;

    for (int i = tid; i < 4 * 16 * 232 * 2 / 16; i += 256)
        ((uint4*)Ps)[i] = make_uint4(0u, 0u, 0u, 0u);

    for (int idx = tid; idx < 232 * 8; idx += 256) {
        int c8 = idx / 232;
        int j  = idx - c8 * 232;
        int c  = c8 * 8;
        uint4 vraw = make_uint4(0u, 0u, 0u, 0u);
        if (j < 197) {
            int tok = (j == 0) ? 0 : (1 + t * PP + (j - 1));
            vraw = *(const uint4*)(qkv + (bb + tok) * QKVN + 1536 + h * 64 + c);
        }
        f16x8 vv = *(f16x8*)&vraw;
#pragma unroll
        for (int e = 0; e < 8; e++) Vt[(c + e) * 232 + j] = vv[e];
    }
    __syncthreads();

    f16* myP = Ps + wave * 16 * 232;
    for (int qt = wave; qt < 13; qt += 4) {
        int mloc = qt * 16 + l15;
        int mc = mloc > 195 ? 195 : mloc;
        const f16* qr = qkv + (bb + 1 + (u64)t * PP + mc) * QKVN + h * 64;
        f16x8 qa0 = *(const f16x8*)(qr + quad * 8);
        f16x8 qa1 = *(const f16x8*)(qr + 32 + quad * 8);

        f32x4 s[13];
#pragma unroll
        for (int nt = 0; nt < 13; nt++) { s[nt][0] = 0.f; s[nt][1] = 0.f; s[nt][2] = 0.f; s[nt][3] = 0.f; }
#pragma unroll
        for (int nt = 0; nt < 13; nt++) {
            int n = nt * 16 + l15;
            int ncl = n > 196 ? 196 : n;
            int tok = (ncl == 0) ? 0 : (1 + t * PP + (ncl - 1));
            const f16* kr = qkv + (bb + tok) * QKVN + 768 + h * 64;
            f16x8 kb0 = *(const f16x8*)(kr + quad * 8);
            f16x8 kb1 = *(const f16x8*)(kr + 32 + quad * 8);
            s[nt] = __builtin_amdgcn_mfma_f32_16x16x32_f16(qa0, kb0, s[nt], 0, 0, 0);
            s[nt] = __builtin_amdgcn_mfma_f32_16x16x32_f16(qa1, kb1, s[nt], 0, 0, 0);
        }
        if (l15 >= 5) { s[12][0] = -1e30f; s[12][1] = -1e30f; s[12][2] = -1e30f; s[12][3] = -1e30f; }

        float mx[4] = {-1e30f, -1e30f, -1e30f, -1e30f};
#pragma unroll
        for (int nt = 0; nt < 13; nt++)
#pragma unroll
            for (int r = 0; r < 4; r++) mx[r] = fmaxf(mx[r], s[nt][r]);
#pragma unroll
        for (int m = 1; m < 16; m <<= 1)
#pragma unroll
            for (int r = 0; r < 4; r++) mx[r] = fmaxf(mx[r], __shfl_xor(mx[r], m, 64));

        float sum[4] = {0.f, 0.f, 0.f, 0.f};
#pragma unroll
        for (int nt = 0; nt < 13; nt++)
#pragma unroll
            for (int r = 0; r < 4; r++) {
                float p = exp2f((s[nt][r] - mx[r]) * 0.18033688011112042f);
                s[nt][r] = p;
                sum[r] += p;
            }
#pragma unroll
        for (int m = 1; m < 16; m <<= 1)
#pragma unroll
            for (int r = 0; r < 4; r++) sum[r] += __shfl_xor(sum[r], m, 64);

#pragma unroll
        for (int nt = 0; nt < 13; nt++)
#pragma unroll
            for (int r = 0; r < 4; r++)
                myP[(quad * 4 + r) * 232 + nt * 16 + l15] = (f16)s[nt][r];

        f32x4 o[4];
#pragma unroll
        for (int n2 = 0; n2 < 4; n2++) { o[n2][0] = 0.f; o[n2][1] = 0.f; o[n2][2] = 0.f; o[n2][3] = 0.f; }
#pragma unroll
        for (int kc = 0; kc < 7; kc++) {
            f16x8 pa = *(const f16x8*)(&myP[l15 * 232 + kc * 32 + quad * 8]);
#pragma unroll
            for (int n2 = 0; n2 < 4; n2++) {
                f16x8 vb = *(const f16x8*)(&Vt[(n2 * 16 + l15) * 232 + kc * 32 + quad * 8]);
                o[n2] = __builtin_amdgcn_mfma_f32_16x16x32_f16(pa, vb, o[n2], 0, 0, 0);
            }
        }

        float inv[4];
#pragma unroll
        for (int r = 0; r < 4; r++) inv[r] = 1.f / sum[r];
#pragma unroll
        for (int n2 = 0; n2 < 4; n2++)
#pragma unroll
            for (int r = 0; r < 4; r++) {
                int m = qt * 16 + quad * 4 + r;
                if (m < PP)
                    ctx[(bb + 1 + (u64)t * PP + m) * DM + h * 64 + n2 * 16 + l15] = (f16)(o[n2][r] * inv[r]);
            }
    }
}

// ---------------- host ----------------
extern "C" void kernel_launch(void* const* d_in, const int* in_sizes, int n_in,
                              void* d_out, int out_size, void* d_ws, size_t ws_size,
                              hipStream_t stream) {
    const float* x_in  = (const float*)d_in[0];
    const float* t_Wq  = (const float*)d_in[1];
    const float* t_bq  = (const float*)d_in[2];
    const float* t_Wk  = (const float*)d_in[3];
    const float* t_bk  = (const float*)d_in[4];
    const float* t_Wv  = (const float*)d_in[5];
    const float* t_bv  = (const float*)d_in[6];
    const float* t_Wo  = (const float*)d_in[7];
    const float* t_bo  = (const float*)d_in[8];
    const float* s_Wq  = (const float*)d_in[9];
    const float* s_bq  = (const float*)d_in[10];
    const float* s_Wk  = (const float*)d_in[11];
    const float* s_bk  = (const float*)d_in[12];
    const float* s_Wv  = (const float*)d_in[13];
    const float* s_bv  = (const float*)d_in[14];
    const float* s_Wo  = (const float*)d_in[15];
    const float* s_bo  = (const float*)d_in[16];
    const float* W1    = (const float*)d_in[17];
    const float* b1    = (const float*)d_in[18];
    const float* W2    = (const float*)d_in[19];
    const float* b2    = (const float*)d_in[20];
    const float* ln1g  = (const float*)d_in[21];
    const float* ln1b  = (const float*)d_in[22];
    const float* ln2g  = (const float*)d_in[23];
    const float* ln2b  = (const float*)d_in[24];
    const float* ln3g  = (const float*)d_in[25];
    const float* ln3b  = (const float*)d_in[26];

    char* ws = (char*)d_ws;
    f16* y    = (f16*)(ws + Y_OFF);
    f16* qkv  = (f16*)(ws + QKV_OFF);
    f16* ctx  = (f16*)(ws + CTX_OFF);
    f16* hbuf = (f16*)(ws + H_OFF);
    float* clsP = (float*)(ws + Y_OFF);   // reuses dead y region
    char* wreg = ws + W_OFF;
    f16* tQKV  = (f16*)(wreg);
    f16* tWoT  = (f16*)(wreg + 3538944);
    f16* sQKV  = (f16*)(wreg + 4718592);
    f16* sWoT  = (f16*)(wreg + 8257536);
    f16* W1T   = (f16*)(wreg + 9437184);
    f16* W2T   = (f16*)(wreg + 14155776);
    float* tBias = (float*)(wreg + 18874368);
    float* sBias = (float*)(wreg + 18883584);
    float* xcur  = (float*)d_out;

    dim3 tb(256);
    // --- weight prep ---
    transpose_kernel<<<dim3(24, 24), tb, 0, stream>>>(t_Wq, tQKV, 768, 768);
    transpose_kernel<<<dim3(24, 24), tb, 0, stream>>>(t_Wk, tQKV + 768 * 768, 768, 768);
    transpose_kernel<<<dim3(24, 24), tb, 0, stream>>>(t_Wv, tQKV + 2 * 768 * 768, 768, 768);
    transpose_kernel<<<dim3(24, 24), tb, 0, stream>>>(t_Wo, tWoT, 768, 768);
    transpose_kernel<<<dim3(24, 24), tb, 0, stream>>>(s_Wq, sQKV, 768, 768);
    transpose_kernel<<<dim3(24, 24), tb, 0, stream>>>(s_Wk, sQKV + 768 * 768, 768, 768);
    transpose_kernel<<<dim3(24, 24), tb, 0, stream>>>(s_Wv, sQKV + 2 * 768 * 768, 768, 768);
    transpose_kernel<<<dim3(24, 24), tb, 0, stream>>>(s_Wo, sWoT, 768, 768);
    transpose_kernel<<<dim3(96, 24), tb, 0, stream>>>(W1, W1T, 768, 3072);
    transpose_kernel<<<dim3(24, 96), tb, 0, stream>>>(W2, W2T, 3072, 768);
    bias3_kernel<<<3, tb, 0, stream>>>(t_bq, t_bk, t_bv, tBias);
    bias3_kernel<<<3, tb, 0, stream>>>(s_bq, s_bk, s_bv, sBias);

    // --- phase A: time MHA ---
    ln_kernel<<<3138, tb, 0, stream>>>(x_in, ln1g, ln1b, y);
    gemm_kernel<QKVN, false, false, true><<<MB_PAD * 18, tb, 0, stream>>>(y, tQKV, tBias, nullptr, nullptr, qkv, 768);
    time_attn_kernel<<<4704, tb, 0, stream>>>(qkv, ctx);
    cls_part_kernel<<<BQ * NH * CCH, tb, 0, stream>>>(qkv, clsP);
    cls_comb_kernel<<<24, tb, 0, stream>>>(clsP, ctx);
    gemm_kernel<DM, false, true, false><<<MB_PAD * 6, tb, 0, stream>>>(ctx, tWoT, t_bo, x_in, xcur, nullptr, 768);

    // --- phase B: space MHA ---
    ln_kernel<<<3138, tb, 0, stream>>>(xcur, ln2g, ln2b, y);
    gemm_kernel<QKVN, false, false, true><<<MB_PAD * 18, tb, 0, stream>>>(y, sQKV, sBias, nullptr, nullptr, qkv, 768);
    space_attn_kernel<<<768, tb, 0, stream>>>(qkv, ctx);
    cls_part_kernel<<<BQ * NH * CCH, tb, 0, stream>>>(qkv, clsP);
    cls_comb_kernel<<<24, tb, 0, stream>>>(clsP, ctx);
    gemm_kernel<DM, false, true, false><<<MB_PAD * 6, tb, 0, stream>>>(ctx, sWoT, s_bo, xcur, xcur, nullptr, 768);

    // --- phase C: MLP ---
    ln_kernel<<<3138, tb, 0, stream>>>(xcur, ln3g, ln3b, y);
    gemm_kernel<D4, true, false, true><<<MB_PAD * 24, tb, 0, stream>>>(y, W1T, b1, nullptr, nullptr, hbuf, 768);
    gemm_kernel<DM, false, true, false><<<MB_PAD * 6, tb, 0, stream>>>(hbuf, W2T, b2, xcur, xcur, nullptr, 3072);
}

// Round 7
// 834.547 us; speedup vs baseline: 1.2964x; 1.2964x over previous
//
#include <hip/hip_runtime.h>

// ---------------- problem constants ----------------
#define BQ   8
#define SQ   1569
#define BS   12552      // BQ*SQ
#define DM   768
#define NH   12
#define DH   64
#define TT   8
#define PP   196
#define D4   3072
#define QKVN 2304
#define CCH  24         // CLS split-K chunks
#define CKEY 66         // keys per chunk (24*66 = 1584 >= 1569)
#define MB_PAD 104      // 99 m-blocks padded to multiple of 8 for XCD-stable swizzle

typedef _Float16 f16;
typedef _Float16 f16x8 __attribute__((ext_vector_type(8)));
typedef float    f32x4 __attribute__((ext_vector_type(4)));
typedef unsigned long long u64;

#define AS1 __attribute__((address_space(1)))
#define AS3 __attribute__((address_space(3)))

#define Y_OFF    0ULL
#define QKV_OFF  19279872ULL
#define CTX_OFF  77119488ULL
#define H_OFF    19279872ULL
#define W_OFF    96399360ULL

// ---------------- LayerNorm (wave per row) ----------------
__global__ __launch_bounds__(256) void ln_kernel(const float* __restrict__ x,
                                                 const float* __restrict__ g,
                                                 const float* __restrict__ bta,
                                                 f16* __restrict__ y) {
    int row = blockIdx.x * 4 + (threadIdx.x >> 6);
    int lane = threadIdx.x & 63;
    if (row >= BS) return;
    const float* xr = x + (u64)row * DM;
    float v[12];
    float s = 0.f, s2 = 0.f;
#pragma unroll
    for (int i = 0; i < 12; i++) { v[i] = xr[lane + i * 64]; s += v[i]; s2 += v[i] * v[i]; }
#pragma unroll
    for (int m = 1; m < 64; m <<= 1) { s += __shfl_xor(s, m, 64); s2 += __shfl_xor(s2, m, 64); }
    float mean = s * (1.f / 768.f);
    float var  = s2 * (1.f / 768.f) - mean * mean;
    float rstd = rsqrtf(var + 1e-12f);
    f16* yr = y + (u64)row * DM;
#pragma unroll
    for (int i = 0; i < 12; i++) {
        int c = lane + i * 64;
        yr[c] = (f16)((v[i] - mean) * rstd * g[c] + bta[c]);
    }
}

// ---------------- merged weight-prep: 10 transposes + 2 bias concats, ONE dispatch ----------------
// Replaces 12 launches (round-6 post-mortem: 27 serial dispatches -> inter-kernel gaps
// are the only untouched cost). Block decode:
//   [0,4608)    : eight 768x768 fp32->f16 transposes (576 blocks each)
//   [4608,6912) : W1  (768x3072), 2304 blocks
//   [6912,9216) : W2  (3072x768), 2304 blocks
//   [9216,9222) : two bias3 concats (3 blocks each)
__global__ __launch_bounds__(256) void prep_kernel(const float* __restrict__ t_Wq,
                                                   const float* __restrict__ t_Wk,
                                                   const float* __restrict__ t_Wv,
                                                   const float* __restrict__ t_Wo,
                                                   const float* __restrict__ s_Wq,
                                                   const float* __restrict__ s_Wk,
                                                   const float* __restrict__ s_Wv,
                                                   const float* __restrict__ s_Wo,
                                                   const float* __restrict__ W1,
                                                   const float* __restrict__ W2,
                                                   const float* __restrict__ t_bq,
                                                   const float* __restrict__ t_bk,
                                                   const float* __restrict__ t_bv,
                                                   const float* __restrict__ s_bq,
                                                   const float* __restrict__ s_bk,
                                                   const float* __restrict__ s_bv,
                                                   f16* __restrict__ tQKV,
                                                   f16* __restrict__ tWoT,
                                                   f16* __restrict__ sQKV,
                                                   f16* __restrict__ sWoT,
                                                   f16* __restrict__ W1T,
                                                   f16* __restrict__ W2T,
                                                   float* __restrict__ tBias,
                                                   float* __restrict__ sBias) {
    int id = blockIdx.x;
    int tid = threadIdx.x;

    if (id >= 9216) {                      // bias concat blocks
        int j = id - 9216;
        const float* a; const float* b; const float* c; float* dst;
        if (j < 3) { a = t_bq; b = t_bk; c = t_bv; dst = tBias; }
        else       { a = s_bq; b = s_bk; c = s_bv; dst = sBias; j -= 3; }
        int i = j * 256 + tid;
        if (i < 768) { dst[i] = a[i]; dst[i + 768] = b[i]; dst[i + 1536] = c[i]; }
        return;
    }

    const float* src; f16* dst; int R, C, bx, by;
    if (id < 4608) {                       // 8 square 768x768 transposes
        int w = id / 576, t = id % 576;
        switch (w) {
            case 0: src = t_Wq; dst = tQKV;                break;
            case 1: src = t_Wk; dst = tQKV + 768 * 768;    break;
            case 2: src = t_Wv; dst = tQKV + 2 * 768 * 768; break;
            case 3: src = t_Wo; dst = tWoT;                break;
            case 4: src = s_Wq; dst = sQKV;                break;
            case 5: src = s_Wk; dst = sQKV + 768 * 768;    break;
            case 6: src = s_Wv; dst = sQKV + 2 * 768 * 768; break;
            default: src = s_Wo; dst = sWoT;               break;
        }
        R = 768; C = 768;
        bx = (t % 24) * 32; by = (t / 24) * 32;
    } else if (id < 6912) {                // W1: 768 x 3072
        int t = id - 4608;
        src = W1; dst = W1T; R = 768; C = 3072;
        bx = (t % 96) * 32; by = (t / 96) * 32;
    } else {                               // W2: 3072 x 768
        int t = id - 6912;
        src = W2; dst = W2T; R = 3072; C = 768;
        bx = (t % 24) * 32; by = (t / 24) * 32;
    }

    __shared__ float tile[32][33];
    int tx = tid & 31, ty = tid >> 5;
#pragma unroll
    for (int i = 0; i < 4; i++) {
        int r = by + ty + i * 8, c = bx + tx;
        if (r < R && c < C) tile[ty + i * 8][tx] = src[(u64)r * C + c];
    }
    __syncthreads();
#pragma unroll
    for (int i = 0; i < 4; i++) {
        int c = bx + ty + i * 8, r = by + tx;
        if (c < C && r < R) dst[(u64)c * R + r] = (f16)tile[tx][ty + i * 8];
    }
}

// ---------------- GEMM v5 (round-0 verified config, 867.9 us): R4 staging + 1-barrier dbuf ----------------
// C = A(BSxK,f16) @ Bt^T (Bt NxK f16) + bias [+gelu][+resid]
// Grid: id = nb*MB_PAD + mb (mb fastest -> id%8 == mb%8, XCD-stable A slices).
// __launch_bounds__(256,4): cap unified VGPR+AGPR at 128/wave -> 4 waves/SIMD.
// NOTE rounds 1-6: five structural variants (256^2 8-phase x3, tri-buffer+counted-vmcnt,
// barrier-free per-wave staging) ALL regressed or were neutral. Lessons banked:
//  - bank-conflict fix verified (7.3M->0) but NULL here: stage+drain+barrier is the
//    2-phase critical path, conflicts are hidden (regime gate).
//  - any variant that pays occupancy (LDS>32KB) or L2 locality for schedule depth loses;
//    v5's 480 TF IS the TLP mechanism. Do not restructure this kernel again.
template <int NOUT, bool GELU, bool RESID, bool OUTF16>
__global__ __launch_bounds__(256, 4) void gemm_kernel(const f16* __restrict__ A,
                                                      const f16* __restrict__ Bt,
                                                      const float* __restrict__ bias,
                                                      const float* __restrict__ resid,
                                                      float* __restrict__ Cf,
                                                      f16* __restrict__ Ch,
                                                      int K) {
    __shared__ __align__(16) f16 As[2][128 * 32];
    __shared__ __align__(16) f16 Bs[2][128 * 32];
    int id = blockIdx.x;
    int mb = id % MB_PAD, nb = id / MB_PAD;
    if (mb >= 99) return;
    int tid  = threadIdx.x;
    int lane = tid & 63, wave = tid >> 6;
    int wm = wave >> 1, wn = wave & 1;
    int m0 = mb * 128, n0 = nb * 128;
    int l15 = lane & 15, quad = lane >> 4;

    int r0   = wave * 16 + (lane >> 2);
    int coff = (lane & 3) * 8;
    const f16* ag0 = A + (u64)(m0 + r0) * K + coff;
    const f16* ag1 = A + (u64)(m0 + r0 + 64) * K + coff;
    bool av0 = (m0 + r0) < BS, av1 = (m0 + r0 + 64) < BS;
    const f16* bg0 = Bt + (u64)(n0 + r0) * K + coff;
    const f16* bg1 = Bt + (u64)(n0 + r0 + 64) * K + coff;
    int lofs = wave * 1024;

    f32x4 acc[4][4];
#pragma unroll
    for (int i = 0; i < 4; i++)
#pragma unroll
        for (int j = 0; j < 4; j++)
#pragma unroll
            for (int r = 0; r < 4; r++) acc[i][j][r] = 0.f;

    if (av0) __builtin_amdgcn_global_load_lds((const AS1 void*)ag0, (AS3 void*)((AS3 char*)&As[0][0] + lofs), 16, 0, 0);
    if (av1) __builtin_amdgcn_global_load_lds((const AS1 void*)ag1, (AS3 void*)((AS3 char*)&As[0][0] + lofs + 4096), 16, 0, 0);
    __builtin_amdgcn_global_load_lds((const AS1 void*)bg0, (AS3 void*)((AS3 char*)&Bs[0][0] + lofs), 16, 0, 0);
    __builtin_amdgcn_global_load_lds((const AS1 void*)bg1, (AS3 void*)((AS3 char*)&Bs[0][0] + lofs + 4096), 16, 0, 0);
    ag0 += 32; ag1 += 32; bg0 += 32; bg1 += 32;

    int nit = K >> 5;
    for (int it = 0; it < nit; it++) {
        __syncthreads();                 // drains staging for buffer it&1
        int buf = it & 1;
        if (it + 1 < nit) {              // prefetch next tile into other buffer
            int nb2 = buf ^ 1;
            if (av0) __builtin_amdgcn_global_load_lds((const AS1 void*)ag0, (AS3 void*)((AS3 char*)&As[nb2][0] + lofs), 16, 0, 0);
            if (av1) __builtin_amdgcn_global_load_lds((const AS1 void*)ag1, (AS3 void*)((AS3 char*)&As[nb2][0] + lofs + 4096), 16, 0, 0);
            __builtin_amdgcn_global_load_lds((const AS1 void*)bg0, (AS3 void*)((AS3 char*)&Bs[nb2][0] + lofs), 16, 0, 0);
            __builtin_amdgcn_global_load_lds((const AS1 void*)bg1, (AS3 void*)((AS3 char*)&Bs[nb2][0] + lofs + 4096), 16, 0, 0);
            ag0 += 32; ag1 += 32; bg0 += 32; bg1 += 32;
        }
        f16x8 af[4], bf[4];
#pragma unroll
        for (int i = 0; i < 4; i++)
            af[i] = *(const f16x8*)(&As[buf][(wm * 64 + i * 16 + l15) * 32 + quad * 8]);
#pragma unroll
        for (int j = 0; j < 4; j++)
            bf[j] = *(const f16x8*)(&Bs[buf][(wn * 64 + j * 16 + l15) * 32 + quad * 8]);
#pragma unroll
        for (int i = 0; i < 4; i++)
#pragma unroll
            for (int j = 0; j < 4; j++)
                acc[i][j] = __builtin_amdgcn_mfma_f32_16x16x32_f16(af[i], bf[j], acc[i][j], 0, 0, 0);
    }

#pragma unroll
    for (int i = 0; i < 4; i++) {
#pragma unroll
        for (int j = 0; j < 4; j++) {
            int col = n0 + wn * 64 + j * 16 + l15;
            float bv = bias[col];
#pragma unroll
            for (int r = 0; r < 4; r++) {
                int row = m0 + wm * 64 + i * 16 + quad * 4 + r;
                if (row < BS) {
                    float v = acc[i][j][r] + bv;
                    if (GELU) {
                        // tanh-approx GELU (max dev ~3e-3 from exact erf form):
                        // gelu(x) = x * sigmoid(2*0.7978845608*(x + 0.044715 x^3))
                        float u = 0.7978845608028654f * (v + 0.044715f * v * v * v);
                        float e = __builtin_exp2f(-2.885390081777927f * u);
                        v = v / (1.f + e);
                    }
                    if (RESID) v += resid[(u64)row * NOUT + col];
                    if (OUTF16) Ch[(u64)row * NOUT + col] = (f16)v;
                    else        Cf[(u64)row * NOUT + col] = v;
                }
            }
        }
    }
}

// ---------------- phase-A attention, merged: time_attn [0,4704) + cls_part [4704,7008) ----------------
// Both read qkv and are independent (time_attn writes ctx patch rows; cls_part writes
// clsP). Merging saves one serial dispatch gap. time_attn uses no LDS, cls_part ~5KB,
// so no occupancy coupling.
__global__ __launch_bounds__(256) void attnA_kernel(const f16* __restrict__ qkv,
                                                    f16* __restrict__ ctx,
                                                    float* __restrict__ part) {
    int tid = threadIdx.x, lane = tid & 63, wave = tid >> 6;
    if (blockIdx.x < 4704) {
        // ---- time attention: wave per (b,h,p); 8 queries x 9 keys ----
        int w = blockIdx.x * 4 + wave;
        int b = w / (NH * PP);
        int rem = w % (NH * PP);
        int h = rem / PP, p = rem % PP;
        u64 bb = (u64)b * SQ;
        int hoff = h * 64 + lane;

        float qv[TT], kv[9], vv[9];
#pragma unroll
        for (int t = 0; t < TT; t++) qv[t] = (float)qkv[(bb + 1 + t * PP + p) * QKVN + hoff];
        kv[0] = (float)qkv[bb * QKVN + 768 + hoff];
        vv[0] = (float)qkv[bb * QKVN + 1536 + hoff];
#pragma unroll
        for (int j = 1; j <= TT; j++) {
            u64 ro = (bb + 1 + (u64)(j - 1) * PP + p) * QKVN;
            kv[j] = (float)qkv[ro + 768 + hoff];
            vv[j] = (float)qkv[ro + 1536 + hoff];
        }
#pragma unroll
        for (int t = 0; t < TT; t++) {
            float s[9];
#pragma unroll
            for (int j = 0; j < 9; j++) {
                float ps = qv[t] * kv[j];
#pragma unroll
                for (int m = 1; m < 64; m <<= 1) ps += __shfl_xor(ps, m, 64);
                s[j] = ps * 0.125f;
            }
            float mx = s[0];
#pragma unroll
            for (int j = 1; j < 9; j++) mx = fmaxf(mx, s[j]);
            float sum = 0.f;
#pragma unroll
            for (int j = 0; j < 9; j++) { s[j] = expf(s[j] - mx); sum += s[j]; }
            float o = 0.f;
#pragma unroll
            for (int j = 0; j < 9; j++) o += s[j] * vv[j];
            o /= sum;
            ctx[(bb + 1 + (u64)t * PP + p) * DM + h * 64 + lane] = (f16)o;
        }
        return;
    }
    // ---- CLS split-K part: block per (b,h,chunk) ----
    {
        int g = blockIdx.x - 4704;
        int c = g % CCH, bh = g / CCH;
        int b = bh / NH, h = bh % NH;
        u64 bb = (u64)b * SQ;
        __shared__ float sc[CKEY];
        __shared__ float accbuf[4][64];
        __shared__ float lbuf[4];
        __shared__ float mxs;
        float qd = (float)qkv[bb * QKVN + h * 64 + lane];
        int j0 = c * CKEY;
        int cnt = SQ - j0; if (cnt > CKEY) cnt = CKEY;
        for (int jj = wave; jj < cnt; jj += 4) {
            float p = qd * (float)qkv[(bb + j0 + jj) * QKVN + 768 + h * 64 + lane];
#pragma unroll
            for (int m = 1; m < 64; m <<= 1) p += __shfl_xor(p, m, 64);
            if (lane == 0) sc[jj] = p * 0.125f;
        }
        __syncthreads();
        if (wave == 0) {
            float m = -1e30f;
            for (int j = lane; j < cnt; j += 64) m = fmaxf(m, sc[j]);
#pragma unroll
            for (int s = 1; s < 64; s <<= 1) m = fmaxf(m, __shfl_xor(m, s, 64));
            if (lane == 0) mxs = m;
        }
        __syncthreads();
        float mx = mxs;
        float acc = 0.f, l = 0.f;
        for (int jj = wave; jj < cnt; jj += 4) {
            float w = expf(sc[jj] - mx);
            l += w;
            acc += w * (float)qkv[(bb + j0 + jj) * QKVN + 1536 + h * 64 + lane];
        }
        accbuf[wave][lane] = acc;
        if (lane == 0) lbuf[wave] = l;
        __syncthreads();
        if (tid < 64) {
            float a = accbuf[0][tid] + accbuf[1][tid] + accbuf[2][tid] + accbuf[3][tid];
            float* pb = part + ((u64)bh * CCH + c) * 66;
            if (tid == 0) { pb[0] = mxs; pb[1] = lbuf[0] + lbuf[1] + lbuf[2] + lbuf[3]; }
            pb[2 + tid] = a;
        }
    }
}

// ---------------- CLS attention split-K: part kernel (phase B), block per (b,h,chunk) ----------------
__global__ __launch_bounds__(256) void cls_part_kernel(const f16* __restrict__ qkv,
                                                       float* __restrict__ part) {
    int g = blockIdx.x;
    int c = g % CCH, bh = g / CCH;
    int b = bh / NH, h = bh % NH;
    u64 bb = (u64)b * SQ;
    int tid = threadIdx.x, lane = tid & 63, wave = tid >> 6;
    __shared__ float sc[CKEY];
    __shared__ float accbuf[4][64];
    __shared__ float lbuf[4];
    __shared__ float mxs;
    float qd = (float)qkv[bb * QKVN + h * 64 + lane];
    int j0 = c * CKEY;
    int cnt = SQ - j0; if (cnt > CKEY) cnt = CKEY;
    for (int jj = wave; jj < cnt; jj += 4) {
        float p = qd * (float)qkv[(bb + j0 + jj) * QKVN + 768 + h * 64 + lane];
#pragma unroll
        for (int m = 1; m < 64; m <<= 1) p += __shfl_xor(p, m, 64);
        if (lane == 0) sc[jj] = p * 0.125f;
    }
    __syncthreads();
    if (wave == 0) {
        float m = -1e30f;
        for (int j = lane; j < cnt; j += 64) m = fmaxf(m, sc[j]);
#pragma unroll
        for (int s = 1; s < 64; s <<= 1) m = fmaxf(m, __shfl_xor(m, s, 64));
        if (lane == 0) mxs = m;
    }
    __syncthreads();
    float mx = mxs;
    float acc = 0.f, l = 0.f;
    for (int jj = wave; jj < cnt; jj += 4) {
        float w = expf(sc[jj] - mx);
        l += w;
        acc += w * (float)qkv[(bb + j0 + jj) * QKVN + 1536 + h * 64 + lane];
    }
    accbuf[wave][lane] = acc;
    if (lane == 0) lbuf[wave] = l;
    __syncthreads();
    if (tid < 64) {
        float a = accbuf[0][tid] + accbuf[1][tid] + accbuf[2][tid] + accbuf[3][tid];
        float* pb = part + ((u64)bh * CCH + c) * 66;
        if (tid == 0) { pb[0] = mxs; pb[1] = lbuf[0] + lbuf[1] + lbuf[2] + lbuf[3]; }
        pb[2 + tid] = a;
    }
}

// ---------------- CLS attention split-K: combine kernel, wave per (b,h) ----------------
__global__ __launch_bounds__(256) void cls_comb_kernel(const float* __restrict__ part,
                                                       f16* __restrict__ ctx) {
    int w = blockIdx.x * 4 + (threadIdx.x >> 6);
    int lane = threadIdx.x & 63;
    if (w >= BQ * NH) return;
    int b = w / NH, h = w % NH;
    const float* pb = part + (u64)w * CCH * 66;
    float m = (lane < CCH) ? pb[lane * 66] : -1e30f;
#pragma unroll
    for (int s = 1; s < 64; s <<= 1) m = fmaxf(m, __shfl_xor(m, s, 64));
    float l = (lane < CCH) ? pb[lane * 66 + 1] * expf(pb[lane * 66] - m) : 0.f;
#pragma unroll
    for (int s = 1; s < 64; s <<= 1) l += __shfl_xor(l, s, 64);
    float o = 0.f;
    for (int j = 0; j < CCH; j++) {
        float mj = pb[j * 66];
        o += pb[j * 66 + 2 + lane] * expf(mj - m);
    }
    ctx[((u64)b * SQ) * DM + h * 64 + lane] = (f16)(o / l);
}

// ---------------- space attention: MFMA flash, block per (b,h,t) ----------------
__global__ __launch_bounds__(256) void space_attn_kernel(const f16* __restrict__ qkv,
                                                         f16* __restrict__ ctx) {
    int g = blockIdx.x;
    int b = g / (NH * TT);
    int rem = g % (NH * TT);
    int h = rem / TT, t = rem % TT;
    __shared__ __align__(16) f16 Vt[64 * 232];
    __shared__ __align__(16) f16 Ps[4 * 16 * 232];
    u64 bb = (u64)b * SQ;
    int tid = threadIdx.x, lane = tid & 63, wave = tid >> 6;
    int l15 = lane & 15, quad = lane >> 4;

    for (int i = tid; i < 4 * 16 * 232 * 2 / 16; i += 256)
        ((uint4*)Ps)[i] = make_uint4(0u, 0u, 0u, 0u);

    for (int idx = tid; idx < 232 * 8; idx += 256) {
        int c8 = idx / 232;
        int j  = idx - c8 * 232;
        int c  = c8 * 8;
        uint4 vraw = make_uint4(0u, 0u, 0u, 0u);
        if (j < 197) {
            int tok = (j == 0) ? 0 : (1 + t * PP + (j - 1));
            vraw = *(const uint4*)(qkv + (bb + tok) * QKVN + 1536 + h * 64 + c);
        }
        f16x8 vv = *(f16x8*)&vraw;
#pragma unroll
        for (int e = 0; e < 8; e++) Vt[(c + e) * 232 + j] = vv[e];
    }
    __syncthreads();

    f16* myP = Ps + wave * 16 * 232;
    for (int qt = wave; qt < 13; qt += 4) {
        int mloc = qt * 16 + l15;
        int mc = mloc > 195 ? 195 : mloc;
        const f16* qr = qkv + (bb + 1 + (u64)t * PP + mc) * QKVN + h * 64;
        f16x8 qa0 = *(const f16x8*)(qr + quad * 8);
        f16x8 qa1 = *(const f16x8*)(qr + 32 + quad * 8);

        f32x4 s[13];
#pragma unroll
        for (int nt = 0; nt < 13; nt++) { s[nt][0] = 0.f; s[nt][1] = 0.f; s[nt][2] = 0.f; s[nt][3] = 0.f; }
#pragma unroll
        for (int nt = 0; nt < 13; nt++) {
            int n = nt * 16 + l15;
            int ncl = n > 196 ? 196 : n;
            int tok = (ncl == 0) ? 0 : (1 + t * PP + (ncl - 1));
            const f16* kr = qkv + (bb + tok) * QKVN + 768 + h * 64;
            f16x8 kb0 = *(const f16x8*)(kr + quad * 8);
            f16x8 kb1 = *(const f16x8*)(kr + 32 + quad * 8);
            s[nt] = __builtin_amdgcn_mfma_f32_16x16x32_f16(qa0, kb0, s[nt], 0, 0, 0);
            s[nt] = __builtin_amdgcn_mfma_f32_16x16x32_f16(qa1, kb1, s[nt], 0, 0, 0);
        }
        if (l15 >= 5) { s[12][0] = -1e30f; s[12][1] = -1e30f; s[12][2] = -1e30f; s[12][3] = -1e30f; }

        float mx[4] = {-1e30f, -1e30f, -1e30f, -1e30f};
#pragma unroll
        for (int nt = 0; nt < 13; nt++)
#pragma unroll
            for (int r = 0; r < 4; r++) mx[r] = fmaxf(mx[r], s[nt][r]);
#pragma unroll
        for (int m = 1; m < 16; m <<= 1)
#pragma unroll
            for (int r = 0; r < 4; r++) mx[r] = fmaxf(mx[r], __shfl_xor(mx[r], m, 64));

        float sum[4] = {0.f, 0.f, 0.f, 0.f};
#pragma unroll
        for (int nt = 0; nt < 13; nt++)
#pragma unroll
            for (int r = 0; r < 4; r++) {
                float p = exp2f((s[nt][r] - mx[r]) * 0.18033688011112042f);
                s[nt][r] = p;
                sum[r] += p;
            }
#pragma unroll
        for (int m = 1; m < 16; m <<= 1)
#pragma unroll
            for (int r = 0; r < 4; r++) sum[r] += __shfl_xor(sum[r], m, 64);

#pragma unroll
        for (int nt = 0; nt < 13; nt++)
#pragma unroll
            for (int r = 0; r < 4; r++)
                myP[(quad * 4 + r) * 232 + nt * 16 + l15] = (f16)s[nt][r];

        f32x4 o[4];
#pragma unroll
        for (int n2 = 0; n2 < 4; n2++) { o[n2][0] = 0.f; o[n2][1] = 0.f; o[n2][2] = 0.f; o[n2][3] = 0.f; }
#pragma unroll
        for (int kc = 0; kc < 7; kc++) {
            f16x8 pa = *(const f16x8*)(&myP[l15 * 232 + kc * 32 + quad * 8]);
#pragma unroll
            for (int n2 = 0; n2 < 4; n2++) {
                f16x8 vb = *(const f16x8*)(&Vt[(n2 * 16 + l15) * 232 + kc * 32 + quad * 8]);
                o[n2] = __builtin_amdgcn_mfma_f32_16x16x32_f16(pa, vb, o[n2], 0, 0, 0);
            }
        }

        float inv[4];
#pragma unroll
        for (int r = 0; r < 4; r++) inv[r] = 1.f / sum[r];
#pragma unroll
        for (int n2 = 0; n2 < 4; n2++)
#pragma unroll
            for (int r = 0; r < 4; r++) {
                int m = qt * 16 + quad * 4 + r;
                if (m < PP)
                    ctx[(bb + 1 + (u64)t * PP + m) * DM + h * 64 + n2 * 16 + l15] = (f16)(o[n2][r] * inv[r]);
            }
    }
}

// ---------------- host ----------------
extern "C" void kernel_launch(void* const* d_in, const int* in_sizes, int n_in,
                              void* d_out, int out_size, void* d_ws, size_t ws_size,
                              hipStream_t stream) {
    const float* x_in  = (const float*)d_in[0];
    const float* t_Wq  = (const float*)d_in[1];
    const float* t_bq  = (const float*)d_in[2];
    const float* t_Wk  = (const float*)d_in[3];
    const float* t_bk  = (const float*)d_in[4];
    const float* t_Wv  = (const float*)d_in[5];
    const float* t_bv  = (const float*)d_in[6];
    const float* t_Wo  = (const float*)d_in[7];
    const float* t_bo  = (const float*)d_in[8];
    const float* s_Wq  = (const float*)d_in[9];
    const float* s_bq  = (const float*)d_in[10];
    const float* s_Wk  = (const float*)d_in[11];
    const float* s_bk  = (const float*)d_in[12];
    const float* s_Wv  = (const float*)d_in[13];
    const float* s_bv  = (const float*)d_in[14];
    const float* s_Wo  = (const float*)d_in[15];
    const float* s_bo  = (const float*)d_in[16];
    const float* W1    = (const float*)d_in[17];
    const float* b1    = (const float*)d_in[18];
    const float* W2    = (const float*)d_in[19];
    const float* b2    = (const float*)d_in[20];
    const float* ln1g  = (const float*)d_in[21];
    const float* ln1b  = (const float*)d_in[22];
    const float* ln2g  = (const float*)d_in[23];
    const float* ln2b  = (const float*)d_in[24];
    const float* ln3g  = (const float*)d_in[25];
    const float* ln3b  = (const float*)d_in[26];

    char* ws = (char*)d_ws;
    f16* y    = (f16*)(ws + Y_OFF);
    f16* qkv  = (f16*)(ws + QKV_OFF);
    f16* ctx  = (f16*)(ws + CTX_OFF);
    f16* hbuf = (f16*)(ws + H_OFF);
    float* clsP = (float*)(ws + Y_OFF);   // reuses dead y region
    char* wreg = ws + W_OFF;
    f16* tQKV  = (f16*)(wreg);
    f16* tWoT  = (f16*)(wreg + 3538944);
    f16* sQKV  = (f16*)(wreg + 4718592);
    f16* sWoT  = (f16*)(wreg + 8257536);
    f16* W1T   = (f16*)(wreg + 9437184);
    f16* W2T   = (f16*)(wreg + 14155776);
    float* tBias = (float*)(wreg + 18874368);
    float* sBias = (float*)(wreg + 18883584);
    float* xcur  = (float*)d_out;

    dim3 tb(256);
    // --- weight prep: single dispatch (was 12) ---
    prep_kernel<<<9222, tb, 0, stream>>>(t_Wq, t_Wk, t_Wv, t_Wo, s_Wq, s_Wk, s_Wv, s_Wo,
                                         W1, W2, t_bq, t_bk, t_bv, s_bq, s_bk, s_bv,
                                         tQKV, tWoT, sQKV, sWoT, W1T, W2T, tBias, sBias);

    // --- phase A: time MHA ---
    ln_kernel<<<3138, tb, 0, stream>>>(x_in, ln1g, ln1b, y);
    gemm_kernel<QKVN, false, false, true><<<MB_PAD * 18, tb, 0, stream>>>(y, tQKV, tBias, nullptr, nullptr, qkv, 768);
    attnA_kernel<<<7008, tb, 0, stream>>>(qkv, ctx, clsP);
    cls_comb_kernel<<<24, tb, 0, stream>>>(clsP, ctx);
    gemm_kernel<DM, false, true, false><<<MB_PAD * 6, tb, 0, stream>>>(ctx, tWoT, t_bo, x_in, xcur, nullptr, 768);

    // --- phase B: space MHA ---
    ln_kernel<<<3138, tb, 0, stream>>>(xcur, ln2g, ln2b, y);
    gemm_kernel<QKVN, false, false, true><<<MB_PAD * 18, tb, 0, stream>>>(y, sQKV, sBias, nullptr, nullptr, qkv, 768);
    space_attn_kernel<<<768, tb, 0, stream>>>(qkv, ctx);
    cls_part_kernel<<<BQ * NH * CCH, tb, 0, stream>>>(qkv, clsP);
    cls_comb_kernel<<<24, tb, 0, stream>>>(clsP, ctx);
    gemm_kernel<DM, false, true, false><<<MB_PAD * 6, tb, 0, stream>>>(ctx, sWoT, s_bo, xcur, xcur, nullptr, 768);

    // --- phase C: MLP ---
    ln_kernel<<<3138, tb, 0, stream>>>(xcur, ln3g, ln3b, y);
    gemm_kernel<D4, true, false, true><<<MB_PAD * 24, tb, 0, stream>>>(y, W1T, b1, nullptr, nullptr, hbuf, 768);
    gemm_kernel<DM, false, true, false><<<MB_PAD * 6, tb, 0, stream>>>(hbuf, W2T, b2, xcur, xcur, nullptr, 3072);
}